// Round 1
// 499.804 us; speedup vs baseline: 1.0783x; 1.0783x over previous
//
#include <hip/hip_runtime.h>
#include <stdint.h>

// Problem shape (fixed by reference): M=8192 (8 shards x 1024), K=N=4096.
// C[m,n] = sum_k A[m,k] * W[n,k]  (weight stored [N,K], transed_weight==0)
#define K_DIM 4096
#define N_DIM 4096
#define BM 256
#define BN 256
#define NTILES (K_DIM / 64)   // 64 K-tiles of width 64
#define NIT (NTILES / 2)      // 32 main-loop iterations (2 K-tiles each)

typedef short short8 __attribute__((ext_vector_type(8)));      // 8 bf16 (MFMA A/B frag)
typedef float f32x4 __attribute__((ext_vector_type(4)));       // MFMA C/D frag
typedef unsigned short ushort_t;
typedef unsigned short ushort8 __attribute__((ext_vector_type(8)));

// fp32 -> bf16 round-to-nearest-even
__device__ __forceinline__ ushort_t f2bf(float f) {
    uint32_t u = __float_as_uint(f);
    u += 0x7FFFu + ((u >> 16) & 1u);
    return (ushort_t)(u >> 16);
}

// Fused cast: first n8a chunks from `a`, next n8w chunks from `w`. 8 elems/thread.
__global__ void cast_to_bf16_2(const float* __restrict__ a, const float* __restrict__ w,
                               ushort_t* __restrict__ out_a, ushort_t* __restrict__ out_w,
                               int n8a, int n8w) {
    int i = blockIdx.x * blockDim.x + threadIdx.x;
    const float* in;
    ushort_t* out;
    int j;
    if (i < n8a) { in = a; out = out_a; j = i; }
    else if (i < n8a + n8w) { in = w; out = out_w; j = i - n8a; }
    else return;
    const float4* p = (const float4*)in + (size_t)j * 2;
    float4 v0 = p[0];
    float4 v1 = p[1];
    ushort8 r;
    r[0] = f2bf(v0.x); r[1] = f2bf(v0.y); r[2] = f2bf(v0.z); r[3] = f2bf(v0.w);
    r[4] = f2bf(v1.x); r[5] = f2bf(v1.y); r[6] = f2bf(v1.z); r[7] = f2bf(v1.w);
    *((ushort8*)out + j) = r;
}

// Raw workgroup barrier: NO implied s_waitcnt (unlike __syncthreads), but with
// compiler memory fences so C-level LDS reads / stage intrinsics cannot be
// hoisted/sunk across phase boundaries.
__device__ __forceinline__ void wgbar() {
    asm volatile("" ::: "memory");
    __builtin_amdgcn_s_barrier();
    asm volatile("" ::: "memory");
}

// ---------------------------------------------------------------------------
// 8-phase 256x256 bf16 GEMM (B^T layout), BK=64 as 2 kk-slices of 32.
// 512 threads = 8 waves (2 M-rows x 4 N-cols), per-wave output 128x64
// (8x4 frags of 16x16, acc = 128 VGPR). LDS = 2 dbuf x 2 kk x (256x32) x {A,B}
// = 128 KiB. Each kk-slice row = 32 bf16 (64 B) = 4 16B chunks; chunk slot
// swizzle q ^ ((row>>1)&3) (verified 0 bank conflicts in prior rounds) applied
// by pre-swizzling the *global* source so global_load_lds's linear
// wave-uniform-base + lane*16 destination constraint is honored.
//
// Schedule per iteration i (tiles t0=2i in buf0, t1=2i+1 in buf1):
//   ph1: read buf0.kk0 (A mih0 + B), stage buf1.A.kk1 <- t1
//   ph2: read buf0.kk0 (A mih1),     stage buf1.B.kk1 <- t1
//   ph3: read buf0.kk1 (A mih0 + B), stage buf0.A.kk0 <- t2
//   ph4: read buf0.kk1 (A mih1),     stage buf0.B.kk0 <- t2, VMCNT(4)
//   ph5: read buf1.kk0 (A mih0 + B), stage buf0.A.kk1 <- t2
//   ph6: read buf1.kk0 (A mih1),     stage buf0.B.kk1 <- t2
//   ph7: read buf1.kk1 (A mih0 + B), stage buf1.A.kk0 <- t3
//   ph8: read buf1.kk1 (A mih1),     stage buf1.B.kk0 <- t3, VMCNT(4)
// Every destination is overwritten only after the barrier following its last
// read; every read is covered by a prior vmcnt(4)+barrier (2 half-tiles =
// 4 loads/wave stay in flight across each wait -> never drains to 0).
// Last iteration clamps t2/t3 to tile 63 (redundant but safe restage) so the
// vmcnt counts are identical every iteration (branch-free).
// ---------------------------------------------------------------------------

#define LDS_A(b, kk) (sA + ((b) * 2 + (kk)) * 8192)
#define LDS_B(b, kk) (sB + ((b) * 2 + (kk)) * 8192)

#define LOAD_AF(af, b, kk, mih) { _Pragma("unroll") for (int t = 0; t < 4; ++t) { \
    int row = wm + (mih) * 64 + t * 16 + row16;                                   \
    af[t] = *(const short8*)(LDS_A(b, kk) + row * 32 + ksw * 8); } }

#define LOAD_BF(bfr, b, kk) { _Pragma("unroll") for (int t = 0; t < 4; ++t) {     \
    int row = wn + t * 16 + row16;                                                \
    bfr[t] = *(const short8*)(LDS_B(b, kk) + row * 32 + ksw * 8); } }

#define MFMA16(mih, af, bfr) { __builtin_amdgcn_s_setprio(1);                     \
    _Pragma("unroll") for (int t = 0; t < 4; ++t)                                 \
    _Pragma("unroll") for (int n = 0; n < 4; ++n)                                 \
        acc[(mih) * 4 + t][n] = __builtin_amdgcn_mfma_f32_16x16x32_bf16(          \
            af[t], bfr[n], acc[(mih) * 4 + t][n], 0, 0, 0);                       \
    __builtin_amdgcn_s_setprio(0); }

#define LGKM0() asm volatile("s_waitcnt lgkmcnt(0)")
#define VMCNT4() asm volatile("s_waitcnt vmcnt(4)" ::: "memory")

__global__ __launch_bounds__(512, 2) void gemm_bf16_8ph(
    const ushort_t* __restrict__ A,   // [M][K] bf16
    const ushort_t* __restrict__ B,   // [N][K] bf16
    float* __restrict__ C)            // [M][N] fp32
{
    __shared__ ushort_t sA[2 * 2 * 8192];   // 64 KB
    __shared__ ushort_t sB[2 * 2 * 8192];   // 64 KB

    // XCD-aware swizzle: 512 blocks, 8 XCDs, 64 consecutive tiles per XCD;
    // n-fastest within (16 n-tiles/row -> 4 A-panel rows per XCD, L2-friendly).
    const int pid0 = blockIdx.x;
    const int pid  = (pid0 & 7) * (int)(gridDim.x >> 3) + (pid0 >> 3);
    const int pid_n = pid & 15;              // N_DIM/BN = 16
    const int pid_m = pid >> 4;
    const int tile_m = pid_m * BM;
    const int tile_n = pid_n * BN;

    const int lane  = threadIdx.x & 63;
    const int wave  = threadIdx.x >> 6;      // 0..7
    const int wm    = (wave >> 2) * 128;     // 2 wave rows
    const int wn    = (wave & 3) * 64;       // 4 wave cols
    const int row16 = lane & 15;
    const int quad  = lane >> 4;
    const int ksw   = quad ^ ((row16 >> 1) & 3);   // read-side chunk slot

    // Per-thread staging geometry. Half-tile = one 256x32 kk-slice = 1024
    // 16B-chunks; 512 threads x 2 chunks (j=0,1). Chunk c: row=c>>2, physical
    // slot c&3 holds logical k-chunk (c&3)^((row>>1)&3).
    int cb[2];
    size_t goff[2];
    #pragma unroll
    for (int j = 0; j < 2; ++j) {
        cb[j] = wave * 64 + j * 512;                 // wave-uniform chunk base
        int c = cb[j] + lane;
        int r = c >> 2;
        int q = (c & 3) ^ ((r >> 1) & 3);
        goff[j] = (size_t)r * K_DIM + q * 8;
    }
    const ushort_t* Abase = A + (size_t)tile_m * K_DIM;
    const ushort_t* Bbase = B + (size_t)tile_n * K_DIM;

    auto STAGE = [&](const ushort_t* gbase, ushort_t* lds, int k0) {
        #pragma unroll
        for (int j = 0; j < 2; ++j) {
            const ushort_t* gp = gbase + goff[j] + k0;
            __builtin_amdgcn_global_load_lds(
                (const __attribute__((address_space(1))) void*)gp,
                (__attribute__((address_space(3))) void*)(lds + cb[j] * 8), 16, 0, 0);
        }
    };

    f32x4 acc[8][4] = {};

    // Prologue: tile0 fully + tile1.kk0 (6 half-tiles = 12 loads/wave).
    STAGE(Abase, LDS_A(0, 0), 0);
    STAGE(Bbase, LDS_B(0, 0), 0);
    STAGE(Abase, LDS_A(0, 1), 32);
    STAGE(Bbase, LDS_B(0, 1), 32);
    STAGE(Abase, LDS_A(1, 0), 64);
    STAGE(Bbase, LDS_B(1, 0), 64);
    VMCNT4();                    // drain tile0's 8 loads; tile1.kk0 stays in flight
    wgbar();

    short8 af[4], bfr[4];

    #pragma unroll 1
    for (int i = 0; i < NIT; ++i) {
        const int k1 = (2 * i + 1) * 64;
        int t2 = 2 * i + 2; if (t2 > NTILES - 1) t2 = NTILES - 1;
        int t3 = 2 * i + 3; if (t3 > NTILES - 1) t3 = NTILES - 1;
        const int k2 = t2 * 64, k3 = t3 * 64;

        // ph1
        LOAD_AF(af, 0, 0, 0); LOAD_BF(bfr, 0, 0);
        STAGE(Abase, LDS_A(1, 1), k1 + 32);
        wgbar(); LGKM0();
        MFMA16(0, af, bfr);
        wgbar();

        // ph2
        LOAD_AF(af, 0, 0, 1);
        STAGE(Bbase, LDS_B(1, 1), k1 + 32);
        wgbar(); LGKM0();
        MFMA16(1, af, bfr);
        wgbar();

        // ph3
        LOAD_AF(af, 0, 1, 0); LOAD_BF(bfr, 0, 1);
        STAGE(Abase, LDS_A(0, 0), k2);
        wgbar(); LGKM0();
        MFMA16(0, af, bfr);
        wgbar();

        // ph4
        LOAD_AF(af, 0, 1, 1);
        STAGE(Bbase, LDS_B(0, 0), k2);
        VMCNT4();
        wgbar(); LGKM0();
        MFMA16(1, af, bfr);
        wgbar();

        // ph5
        LOAD_AF(af, 1, 0, 0); LOAD_BF(bfr, 1, 0);
        STAGE(Abase, LDS_A(0, 1), k2 + 32);
        wgbar(); LGKM0();
        MFMA16(0, af, bfr);
        wgbar();

        // ph6
        LOAD_AF(af, 1, 0, 1);
        STAGE(Bbase, LDS_B(0, 1), k2 + 32);
        wgbar(); LGKM0();
        MFMA16(1, af, bfr);
        wgbar();

        // ph7
        LOAD_AF(af, 1, 1, 0); LOAD_BF(bfr, 1, 1);
        STAGE(Abase, LDS_A(1, 0), k3);
        wgbar(); LGKM0();
        MFMA16(0, af, bfr);
        wgbar();

        // ph8
        LOAD_AF(af, 1, 1, 1);
        STAGE(Bbase, LDS_B(1, 0), k3);
        VMCNT4();
        wgbar(); LGKM0();
        MFMA16(1, af, bfr);
        wgbar();
    }

    // Epilogue: C/D layout col=lane&15, row=quad*4+reg (carried over verified).
    #pragma unroll
    for (int mi = 0; mi < 8; ++mi) {
        #pragma unroll
        for (int r = 0; r < 4; ++r) {
            int m = tile_m + wm + mi * 16 + quad * 4 + r;
            float* crow = C + (size_t)m * N_DIM + tile_n + wn;
            #pragma unroll
            for (int n = 0; n < 4; ++n)
                crow[n * 16 + row16] = acc[mi][n][r];
        }
    }
}

// Safety-net fallback (ws too small / unexpected shape).
__global__ void gemm_naive_f32(const float* __restrict__ A, const float* __restrict__ W,
                               float* __restrict__ C, int m_tot) {
    int n = blockIdx.x * blockDim.x + threadIdx.x;
    int m = blockIdx.y;
    if (n >= N_DIM || m >= m_tot) return;
    const float* a = A + (size_t)m * K_DIM;
    const float* w = W + (size_t)n * K_DIM;
    float s = 0.f;
    for (int k = 0; k < K_DIM; ++k) s += a[k] * w[k];
    C[(size_t)m * N_DIM + n] = s;
}

extern "C" void kernel_launch(void* const* d_in, const int* in_sizes, int n_in,
                              void* d_out, int out_size, void* d_ws, size_t ws_size,
                              hipStream_t stream) {
    const float* a_f32 = (const float*)d_in[0];   // [8192,4096]
    const float* w_f32 = (const float*)d_in[1];   // [4096,4096] ([N,K])
    float* out = (float*)d_out;

    const size_t a_elems = (size_t)in_sizes[0];
    const size_t w_elems = (size_t)in_sizes[1];
    const int m_tot = (int)(a_elems / K_DIM);     // 8192

    const size_t need = (a_elems + w_elems) * sizeof(ushort_t);
    if (ws_size >= need && (m_tot % BM) == 0 && w_elems == (size_t)N_DIM * K_DIM) {
        ushort_t* a_bf = (ushort_t*)d_ws;
        ushort_t* w_bf = a_bf + a_elems;

        int n8a = (int)(a_elems / 8);
        int n8w = (int)(w_elems / 8);
        int n8 = n8a + n8w;
        cast_to_bf16_2<<<(n8 + 255) / 256, 256, 0, stream>>>(a_f32, w_f32, a_bf, w_bf, n8a, n8w);

        int nblocks = (N_DIM / BN) * (m_tot / BM);   // 16 x 32 = 512
        gemm_bf16_8ph<<<nblocks, 512, 0, stream>>>(a_bf, w_bf, out);
    } else {
        dim3 grid(N_DIM / 256, m_tot);
        gemm_naive_f32<<<grid, 256, 0, stream>>>(a_f32, w_f32, out, m_tot);
    }
}